// Round 1
// baseline (474.095 us; speedup 1.0000x reference)
//
#include <hip/hip_runtime.h>

// Problem constants
// x:(4096,8,1024) f32, U:(8,1048576,4) f32, V:(4,1048576,4) f32,
// scale:(8,1), biasq:(8,1), bias:(8,1024)  -> out:(4096,8,1024) f32
// D = 1024*1024 = 2^20, B=4096, N=8, K=4, BW=4, T=1.0

typedef __attribute__((ext_vector_type(8))) short short8;
typedef __attribute__((ext_vector_type(4))) float f32x4;
typedef __attribute__((ext_vector_type(4))) unsigned short ushort4v;

__device__ __forceinline__ unsigned short f2bf(float f) {
  union { float f; unsigned u; } a; a.f = f;
  unsigned u = a.u;
  u += 0x7fffu + ((u >> 16) & 1u);   // RNE; inputs are finite
  return (unsigned short)(u >> 16);
}

// ---------------------------------------------------------------------------
// Kernel 1: cast x fp32 -> bf16, repack [b][n][d1] -> [n][b][d1]
// ---------------------------------------------------------------------------
__global__ __launch_bounds__(256) void xcast_kernel(
    const float4* __restrict__ X4, ushort4v* __restrict__ Xb4) {
  const size_t idx = (size_t)blockIdx.x * 256 + threadIdx.x;  // 8388608 total
  const float4 v = X4[idx];
  const size_t flat = idx << 2;
  const int d1 = (int)(flat & 1023);
  const size_t nb = flat >> 10;
  const int nn = (int)(nb & 7);
  const size_t b = nb >> 3;
  ushort4v o;
  o.x = f2bf(v.x); o.y = f2bf(v.y); o.z = f2bf(v.z); o.w = f2bf(v.w);
  Xb4[(((size_t)nn << 22) + (b << 10) + (size_t)d1) >> 2] = o;
}

// ---------------------------------------------------------------------------
// Kernel 2: weight synthesis. For each d: Theta[n,b,d]=dot4(U[n,d,:],V[b,d,:]),
// sigmoid(clip(.,-10,10)), integer = sum_b s*2^b, w = scale*(integer-biasq-16).
// All 8 n per block so V is read once. Output W^T bf16: Wt[n][l=d2][d1].
// Transpose via padded LDS tiles (stride 33 -> conflict-free).
// ---------------------------------------------------------------------------
__global__ __launch_bounds__(256) void wgen_kernel(
    const float4* __restrict__ U4, const float4* __restrict__ V4,
    const float* __restrict__ scale, const float* __restrict__ biasq,
    unsigned short* __restrict__ Wt) {
  __shared__ float tiles[8][32][33];
  const int t = threadIdx.x;
  const int d1_0 = blockIdx.x * 32;
  const int d2_0 = blockIdx.y * 32;
#pragma unroll
  for (int i = 0; i < 4; i++) {
    const int e = t + 256 * i;
    const int r = e >> 5, c = e & 31;          // r: d1 offset, c: d2 offset
    const size_t d = (size_t)(d1_0 + r) * 1024 + (size_t)(d2_0 + c);
    float4 u[8];
#pragma unroll
    for (int nn = 0; nn < 8; nn++) u[nn] = U4[((size_t)nn << 20) + d];
    float integ[8];
#pragma unroll
    for (int nn = 0; nn < 8; nn++) integ[nn] = 0.f;
#pragma unroll
    for (int b = 0; b < 4; b++) {
      const float4 v = V4[((size_t)b << 20) + d];
      const float pw = (float)(1 << b);
#pragma unroll
      for (int nn = 0; nn < 8; nn++) {
        float th = u[nn].x * v.x + u[nn].y * v.y + u[nn].z * v.z + u[nn].w * v.w;
        th = fminf(10.f, fmaxf(-10.f, th));
        integ[nn] += pw / (1.f + __expf(-th));
      }
    }
#pragma unroll
    for (int nn = 0; nn < 8; nn++) tiles[nn][r][c] = integ[nn];
  }
  __syncthreads();
#pragma unroll
  for (int i = 0; i < 4; i++) {
    const int e = t + 256 * i;
    const int orow = e >> 5, oc = e & 31;      // orow: d2(l) offset, oc: d1 offset
#pragma unroll
    for (int nn = 0; nn < 8; nn++) {
      const float wval = scale[nn] * (tiles[nn][oc][orow] - biasq[nn] - 16.f);
      Wt[((size_t)nn << 20) + (size_t)(d2_0 + orow) * 1024 + (size_t)(d1_0 + oc)] =
          f2bf(wval);
    }
  }
}

// ---------------------------------------------------------------------------
// Kernel 3: batched bf16 GEMM (m97 structure).
// Per n: C(4096x1024) = Xb_n(4096x1024) * Wt_n^T, + bias[n][:].
// 128x128 tile, BK=32, 4 waves (2x2), each wave 4x4 mfma_f32_16x16x32_bf16.
// Staging via global_load_lds width=16 (wave-uniform LDS base + lane*16).
// ---------------------------------------------------------------------------
#define AS1(p) ((const __attribute__((address_space(1))) void*)(p))
#define AS3(p) ((__attribute__((address_space(3))) void*)(p))

__global__ __launch_bounds__(256) void gemm_kernel(
    const unsigned short* __restrict__ Xb,   // [8][4096][1024] bf16
    const unsigned short* __restrict__ Wt,   // [8][1024(l)][1024(d1)] bf16
    const float* __restrict__ bias,          // [8][1024]
    float* __restrict__ out) {               // [4096][8][1024]
  __shared__ unsigned short As[128 * 32];
  __shared__ unsigned short Bs[128 * 32];
  const int t = threadIdx.x;
  const int wv = t >> 6;
  const int ln = t & 63;
  const int n = blockIdx.z;
  const int bm0 = blockIdx.x * 128;
  const int bn0 = blockIdx.y * 128;

  const unsigned short* Ag = Xb + ((size_t)n << 22);
  const unsigned short* Bg = Wt + ((size_t)n << 20);

  // staging: round r covers rows r*64..r*64+63; lane -> row sr, k-offset sk
  const int sr = wv * 16 + (ln >> 2);
  const int sk = (ln & 3) * 8;
  const unsigned short* a0 = Ag + (size_t)(bm0 + sr) * 1024 + sk;
  const unsigned short* a1 = a0 + 64 * 1024;
  const unsigned short* b0 = Bg + (size_t)(bn0 + sr) * 1024 + sk;
  const unsigned short* b1 = b0 + 64 * 1024;
  unsigned short* lA0 = As + wv * 512;          // wave-uniform LDS bases
  unsigned short* lA1 = As + 2048 + wv * 512;
  unsigned short* lB0 = Bs + wv * 512;
  unsigned short* lB1 = Bs + 2048 + wv * 512;

  const int wm = wv >> 1, wn = wv & 1;
  const int lm = ln & 15;
  const int lk = (ln >> 4) * 8;
  const unsigned short* a_rd = As + (wm * 64 + lm) * 32 + lk;
  const unsigned short* b_rd = Bs + (wn * 64 + lm) * 32 + lk;

  f32x4 acc[4][4];
#pragma unroll
  for (int i = 0; i < 4; i++)
#pragma unroll
    for (int j = 0; j < 4; j++) acc[i][j] = (f32x4){0.f, 0.f, 0.f, 0.f};

  for (int k0 = 0; k0 < 1024; k0 += 32) {
    __builtin_amdgcn_global_load_lds(AS1(a0 + k0), AS3(lA0), 16, 0, 0);
    __builtin_amdgcn_global_load_lds(AS1(a1 + k0), AS3(lA1), 16, 0, 0);
    __builtin_amdgcn_global_load_lds(AS1(b0 + k0), AS3(lB0), 16, 0, 0);
    __builtin_amdgcn_global_load_lds(AS1(b1 + k0), AS3(lB1), 16, 0, 0);
    __syncthreads();
    short8 af[4], bfr[4];
#pragma unroll
    for (int i = 0; i < 4; i++) af[i] = *(const short8*)(a_rd + i * 512);
#pragma unroll
    for (int j = 0; j < 4; j++) bfr[j] = *(const short8*)(b_rd + j * 512);
#pragma unroll
    for (int i = 0; i < 4; i++)
#pragma unroll
      for (int j = 0; j < 4; j++)
        acc[i][j] =
            __builtin_amdgcn_mfma_f32_16x16x32_bf16(af[i], bfr[j], acc[i][j], 0, 0, 0);
    __syncthreads();
  }

  // Epilogue: C/D layout col=lane&15, row=(lane>>4)*4+reg  [m89/m91]
  const int q = ln >> 4;
  const int row0 = bm0 + wm * 64 + q * 4;
  const int col0 = bn0 + wn * 64 + lm;
  float bv[4];
#pragma unroll
  for (int j = 0; j < 4; j++) bv[j] = bias[n * 1024 + col0 + j * 16];
#pragma unroll
  for (int i = 0; i < 4; i++) {
#pragma unroll
    for (int r = 0; r < 4; r++) {
      const int row = row0 + i * 16 + r;
      float* op = out + ((size_t)row * 8 + (size_t)n) * 1024;
#pragma unroll
      for (int j = 0; j < 4; j++) op[col0 + j * 16] = acc[i][j][r] + bv[j];
    }
  }
}

// ---------------------------------------------------------------------------
extern "C" void kernel_launch(void* const* d_in, const int* in_sizes, int n_in,
                              void* d_out, int out_size, void* d_ws, size_t ws_size,
                              hipStream_t stream) {
  const float* x     = (const float*)d_in[0];
  const float* U     = (const float*)d_in[1];
  const float* V     = (const float*)d_in[2];
  const float* scale = (const float*)d_in[3];
  const float* biasq = (const float*)d_in[4];
  const float* bias  = (const float*)d_in[5];
  float* out = (float*)d_out;

  // workspace: Xb bf16 [8][4096][1024] = 64 MiB, Wt bf16 [8][1024][1024] = 16 MiB
  unsigned short* Xb = (unsigned short*)d_ws;
  unsigned short* Wt = (unsigned short*)((char*)d_ws + (size_t)67108864);

  xcast_kernel<<<32768, 256, 0, stream>>>((const float4*)x, (ushort4v*)Xb);
  wgen_kernel<<<dim3(32, 32), 256, 0, stream>>>((const float4*)U, (const float4*)V,
                                                scale, biasq, Wt);
  gemm_kernel<<<dim3(32, 8, 8), 256, 0, stream>>>(Xb, Wt, bias, out);
}

// Round 2
// 469.059 us; speedup vs baseline: 1.0107x; 1.0107x over previous
//
#include <hip/hip_runtime.h>

// Problem constants
// x:(4096,8,1024) f32, U:(8,1048576,4) f32, V:(4,1048576,4) f32,
// scale:(8,1), biasq:(8,1), bias:(8,1024)  -> out:(4096,8,1024) f32
// D = 1024*1024 = 2^20, B=4096, N=8, K=4, BW=4, T=1.0

typedef __attribute__((ext_vector_type(8))) short short8;
typedef __attribute__((ext_vector_type(4))) float f32x4;
typedef __attribute__((ext_vector_type(4))) unsigned short ushort4v;

__device__ __forceinline__ unsigned short f2bf(float f) {
  union { float f; unsigned u; } a; a.f = f;
  unsigned u = a.u;
  u += 0x7fffu + ((u >> 16) & 1u);   // RNE; inputs are finite
  return (unsigned short)(u >> 16);
}

// ---------------------------------------------------------------------------
// Kernel 1: cast x fp32 -> bf16, repack [b][n][d1] -> [n][b][d1]
// ---------------------------------------------------------------------------
__global__ __launch_bounds__(256) void xcast_kernel(
    const float4* __restrict__ X4, ushort4v* __restrict__ Xb4) {
  const size_t idx = (size_t)blockIdx.x * 256 + threadIdx.x;  // 8388608 total
  const float4 v = X4[idx];
  const size_t flat = idx << 2;
  const int d1 = (int)(flat & 1023);
  const size_t nb = flat >> 10;
  const int nn = (int)(nb & 7);
  const size_t b = nb >> 3;
  ushort4v o;
  o.x = f2bf(v.x); o.y = f2bf(v.y); o.z = f2bf(v.z); o.w = f2bf(v.w);
  Xb4[(((size_t)nn << 22) + (b << 10) + (size_t)d1) >> 2] = o;
}

// ---------------------------------------------------------------------------
// Kernel 2: weight synthesis -> W^T bf16: Wt[n][l=d2][d1]
// ---------------------------------------------------------------------------
__global__ __launch_bounds__(256) void wgen_kernel(
    const float4* __restrict__ U4, const float4* __restrict__ V4,
    const float* __restrict__ scale, const float* __restrict__ biasq,
    unsigned short* __restrict__ Wt) {
  __shared__ float tiles[8][32][33];
  const int t = threadIdx.x;
  const int d1_0 = blockIdx.x * 32;
  const int d2_0 = blockIdx.y * 32;
#pragma unroll
  for (int i = 0; i < 4; i++) {
    const int e = t + 256 * i;
    const int r = e >> 5, c = e & 31;          // r: d1 offset, c: d2 offset
    const size_t d = (size_t)(d1_0 + r) * 1024 + (size_t)(d2_0 + c);
    float4 u[8];
#pragma unroll
    for (int nn = 0; nn < 8; nn++) u[nn] = U4[((size_t)nn << 20) + d];
    float integ[8];
#pragma unroll
    for (int nn = 0; nn < 8; nn++) integ[nn] = 0.f;
#pragma unroll
    for (int b = 0; b < 4; b++) {
      const float4 v = V4[((size_t)b << 20) + d];
      const float pw = (float)(1 << b);
#pragma unroll
      for (int nn = 0; nn < 8; nn++) {
        float th = u[nn].x * v.x + u[nn].y * v.y + u[nn].z * v.z + u[nn].w * v.w;
        th = fminf(10.f, fmaxf(-10.f, th));
        integ[nn] += pw / (1.f + __expf(-th));
      }
    }
#pragma unroll
    for (int nn = 0; nn < 8; nn++) tiles[nn][r][c] = integ[nn];
  }
  __syncthreads();
#pragma unroll
  for (int i = 0; i < 4; i++) {
    const int e = t + 256 * i;
    const int orow = e >> 5, oc = e & 31;      // orow: d2(l) offset, oc: d1 offset
#pragma unroll
    for (int nn = 0; nn < 8; nn++) {
      const float wval = scale[nn] * (tiles[nn][oc][orow] - biasq[nn] - 16.f);
      Wt[((size_t)nn << 20) + (size_t)(d2_0 + orow) * 1024 + (size_t)(d1_0 + oc)] =
          f2bf(wval);
    }
  }
}

// ---------------------------------------------------------------------------
// Kernel 3: batched bf16 GEMM. BK=64 (32 barriers instead of 64),
// XOR-swizzled LDS (16B chunk slot = global_chunk ^ (row&7)) -> 2-way max
// bank aliasing on fragment reads (free per m136).
// 128x128 tile, 4 waves (2x2), each wave 4x4 mfma_f32_16x16x32_bf16.
// ---------------------------------------------------------------------------
#define AS1(p) ((const __attribute__((address_space(1))) void*)(p))
#define AS3(p) ((__attribute__((address_space(3))) void*)(p))

__global__ __launch_bounds__(256) void gemm_kernel(
    const unsigned short* __restrict__ Xb,   // [8][4096][1024] bf16
    const unsigned short* __restrict__ Wt,   // [8][1024(l)][1024(d1)] bf16
    const float* __restrict__ bias,          // [8][1024]
    float* __restrict__ out) {               // [4096][8][1024]
  __shared__ unsigned short As[128 * 64];    // 16 KiB
  __shared__ unsigned short Bs[128 * 64];    // 16 KiB
  const int t = threadIdx.x;
  const int wv = t >> 6;
  const int ln = t & 63;
  const int n = blockIdx.z;
  const int bm0 = blockIdx.x * 128;
  const int bn0 = blockIdx.y * 128;

  const unsigned short* Ag = Xb + ((size_t)n << 22);
  const unsigned short* Bg = Wt + ((size_t)n << 20);

  // staging: each wave-instruction covers 32 rows (8 per wave), 8 chunks/row.
  // lane -> row sr, LDS chunk slot (ln&7); loads global chunk (ln&7)^(sr&7).
  const int sr = wv * 8 + (ln >> 3);                 // 0..31
  const int sk = (((ln & 7) ^ (sr & 7)) * 8);        // shorts
  const unsigned short* ag = Ag + (size_t)(bm0 + sr) * 1024 + sk;
  const unsigned short* bg = Bg + (size_t)(bn0 + sr) * 1024 + sk;
  unsigned short* lA = As + wv * 512;                // wave-uniform LDS bases
  unsigned short* lB = Bs + wv * 512;

  const int wm = wv >> 1, wn = wv & 1;
  const int lm = ln & 15;
  const int cq = ln >> 4;                            // k-quarter 0..3
  const int sw = lm & 7;                             // row swizzle key
  const unsigned short* a_rd = As + (wm * 64 + lm) * 64;
  const unsigned short* b_rd = Bs + (wn * 64 + lm) * 64;

  f32x4 acc[4][4];
#pragma unroll
  for (int i = 0; i < 4; i++)
#pragma unroll
    for (int j = 0; j < 4; j++) acc[i][j] = (f32x4){0.f, 0.f, 0.f, 0.f};

  for (int k0 = 0; k0 < 1024; k0 += 64) {
#pragma unroll
    for (int r = 0; r < 4; r++) {
      __builtin_amdgcn_global_load_lds(AS1(ag + (size_t)(32 * r) * 1024 + k0),
                                       AS3(lA + r * 2048), 16, 0, 0);
      __builtin_amdgcn_global_load_lds(AS1(bg + (size_t)(32 * r) * 1024 + k0),
                                       AS3(lB + r * 2048), 16, 0, 0);
    }
    __syncthreads();
#pragma unroll
    for (int half = 0; half < 2; half++) {
      const int off = ((half * 4 + cq) ^ sw) * 8;    // swizzled 16B chunk
      short8 af[4], bfr[4];
#pragma unroll
      for (int i = 0; i < 4; i++) af[i] = *(const short8*)(a_rd + i * 1024 + off);
#pragma unroll
      for (int j = 0; j < 4; j++) bfr[j] = *(const short8*)(b_rd + j * 1024 + off);
#pragma unroll
      for (int i = 0; i < 4; i++)
#pragma unroll
        for (int j = 0; j < 4; j++)
          acc[i][j] = __builtin_amdgcn_mfma_f32_16x16x32_bf16(af[i], bfr[j],
                                                              acc[i][j], 0, 0, 0);
    }
    __syncthreads();
  }

  // Epilogue: C/D layout col=lane&15, row=(lane>>4)*4+reg  [m89/m91]
  const int q = ln >> 4;
  const int row0 = bm0 + wm * 64 + q * 4;
  const int col0 = bn0 + wn * 64 + lm;
  float bv[4];
#pragma unroll
  for (int j = 0; j < 4; j++) bv[j] = bias[n * 1024 + col0 + j * 16];
#pragma unroll
  for (int i = 0; i < 4; i++) {
#pragma unroll
    for (int r = 0; r < 4; r++) {
      const int row = row0 + i * 16 + r;
      float* op = out + ((size_t)row * 8 + (size_t)n) * 1024;
#pragma unroll
      for (int j = 0; j < 4; j++) op[col0 + j * 16] = acc[i][j][r] + bv[j];
    }
  }
}

// ---------------------------------------------------------------------------
extern "C" void kernel_launch(void* const* d_in, const int* in_sizes, int n_in,
                              void* d_out, int out_size, void* d_ws, size_t ws_size,
                              hipStream_t stream) {
  const float* x     = (const float*)d_in[0];
  const float* U     = (const float*)d_in[1];
  const float* V     = (const float*)d_in[2];
  const float* scale = (const float*)d_in[3];
  const float* biasq = (const float*)d_in[4];
  const float* bias  = (const float*)d_in[5];
  float* out = (float*)d_out;

  // workspace: Xb bf16 [8][4096][1024] = 64 MiB, Wt bf16 [8][1024][1024] = 16 MiB
  unsigned short* Xb = (unsigned short*)d_ws;
  unsigned short* Wt = (unsigned short*)((char*)d_ws + (size_t)67108864);

  xcast_kernel<<<32768, 256, 0, stream>>>((const float4*)x, (ushort4v*)Xb);
  wgen_kernel<<<dim3(32, 32), 256, 0, stream>>>((const float4*)U, (const float4*)V,
                                                scale, biasq, Wt);
  gemm_kernel<<<dim3(32, 8, 8), 256, 0, stream>>>(Xb, Wt, bias, out);
}